// Round 6
// baseline (340.316 us; speedup 1.0000x reference)
//
#include <hip/hip_runtime.h>
#include <hip/hip_bf16.h>

#define D 128
#define CH 4096   // edges per block in CSR partition passes

typedef unsigned int u32;
typedef unsigned short u16;
typedef __attribute__((ext_vector_type(8))) short s16x8;
typedef __attribute__((ext_vector_type(4))) float f32x4;
typedef __attribute__((ext_vector_type(2))) float f32x2;
typedef __attribute__((ext_vector_type(4))) u32 u32x4;

__device__ __forceinline__ float bf2f(u16 u) {
    union { u32 u; float f; } v; v.u = ((u32)u) << 16; return v.f;
}
__device__ __forceinline__ u16 f2bf(float f) {
    union { float f; u32 u; } v; v.f = f;
    return (u16)((v.u + 0x7fffu + ((v.u >> 16) & 1u)) >> 16);
}
__device__ __forceinline__ u32 pack_bf2(float a, float b) {
    __hip_bfloat162 t = __float22bfloat162_rn(make_float2(a, b));
    union { __hip_bfloat162 t; u32 u; } v; v.t = t; return v.u;
}
__device__ __forceinline__ void unpack2(u32 u, float& lo, float& hi) {
    union { u32 u; float f; } a, b;
    a.u = u << 16; b.u = u & 0xffff0000u;
    lo = a.f; hi = b.f;
}

// ---- dtype detector: flag=0 -> inputs bf16, flag=1 -> fp32 ----
__global__ void detect_dtype(const u16* __restrict__ x, int* __restrict__ flag) {
    __shared__ int cnt;
    if (threadIdx.x == 0) cnt = 0;
    __syncthreads();
    u16 u = x[2 * threadIdx.x];
    int e = (u >> 7) & 0xFF;
    if (e >= 96 && e <= 150) atomicAdd(&cnt, 1);
    __syncthreads();
    if (threadIdx.x == 0) *flag = (cnt >= 128) ? 0 : 1;
}

// ---- canonicalize (body only runs when inputs are fp32) ----
__global__ __launch_bounds__(256)
void to_bf16_all(const void* __restrict__ s0, const void* __restrict__ s1,
                 const void* __restrict__ s2, const void* __restrict__ s3,
                 const void* __restrict__ s4, const void* __restrict__ s5,
                 const void* __restrict__ s6,
                 u16* __restrict__ d0, u16* __restrict__ d1, u16* __restrict__ d2,
                 u16* __restrict__ d3, u16* __restrict__ d4, u16* __restrict__ d5,
                 u16* __restrict__ d6,
                 long long n0, long long n1, long long n2, long long n3,
                 long long n4, long long n5, long long n6,
                 const int* __restrict__ flag)
{
    if (*flag == 0) return;
    long long i = (long long)blockIdx.x * 256 + threadIdx.x;
    const void* s; u16* d; long long off;
    if      (i < n0)                   { s = s0; d = d0; off = i; }
    else if (i < n0+n1)                { s = s1; d = d1; off = i-n0; }
    else if (i < n0+n1+n2)             { s = s2; d = d2; off = i-n0-n1; }
    else if (i < n0+n1+n2+n3)          { s = s3; d = d3; off = i-n0-n1-n2; }
    else if (i < n0+n1+n2+n3+n4)       { s = s4; d = d4; off = i-n0-n1-n2-n3; }
    else if (i < n0+n1+n2+n3+n4+n5)    { s = s5; d = d5; off = i-n0-n1-n2-n3-n4; }
    else if (i < n0+n1+n2+n3+n4+n5+n6) { s = s6; d = d6; off = i-n0-n1-n2-n3-n4-n5; }
    else return;
    d[off] = f2bf(((const float*)s)[off]);
}

__global__ __launch_bounds__(256)
void zero_ints(int* __restrict__ a, int n) {
    int i = blockIdx.x * 256 + threadIdx.x;
    if (i < n) a[i] = 0;
}

// ==== bucketed CSR2 build: key = (dst, r). bucket = dst>>8. needs R<=8, N<2^21 ====
__global__ __launch_bounds__(256)
void csr_count(const int* __restrict__ dst, int* __restrict__ gcnt, int E, int nbuck) {
    __shared__ int scnt[256];
    int tid = threadIdx.x;
    scnt[tid] = 0;
    __syncthreads();
    int base = blockIdx.x * CH;
#pragma unroll
    for (int it = 0; it < CH / 256; ++it) {
        int e = base + it * 256 + tid;
        if (e < E) atomicAdd(&scnt[dst[e] >> 8], 1);
    }
    __syncthreads();
    if (tid < nbuck && scnt[tid] > 0) atomicAdd(&gcnt[tid], scnt[tid]);
}

// scan bucket counts -> bstart[0..nbuck] + bcur copy; also offs2[N*R] = E
__global__ __launch_bounds__(256)
void csr_scan(const int* __restrict__ gcnt, int* __restrict__ bstart, int* __restrict__ bcur,
              int nbuck, int NR, int E_, int* __restrict__ offs2) {
    __shared__ int wpart[4];
    int tid = threadIdx.x, lane = tid & 63, wid = tid >> 6;
    int v = (tid < nbuck) ? gcnt[tid] : 0;
    int s = v;
#pragma unroll
    for (int off = 1; off < 64; off <<= 1) {
        int t = __shfl_up(s, off, 64);
        if (lane >= off) s += t;
    }
    if (lane == 63) wpart[wid] = s;
    __syncthreads();
    int add = 0;
    for (int w = 0; w < wid; ++w) add += wpart[w];
    int excl = add + s - v;
    if (tid <= nbuck) bstart[tid] = excl;
    if (tid < nbuck)  bcur[tid]  = excl;
    if (tid == 0) offs2[NR] = E_;
}

// partition edges into bucket-contiguous ebuf; rec = dstlo<<24 | r<<21 | src
__global__ __launch_bounds__(256)
void csr_part(const int* __restrict__ src, const int* __restrict__ dst,
              const int* __restrict__ et, int* __restrict__ bcur,
              u32* __restrict__ ebuf, int E, int nbuck) {
    __shared__ int scnt[256], sbase[256];
    int tid = threadIdx.x;
    scnt[tid] = 0;
    __syncthreads();
    int base = blockIdx.x * CH;
#pragma unroll
    for (int it = 0; it < CH / 256; ++it) {
        int e = base + it * 256 + tid;
        if (e < E) atomicAdd(&scnt[dst[e] >> 8], 1);
    }
    __syncthreads();
    if (tid < nbuck) {
        int c = scnt[tid];
        sbase[tid] = c ? atomicAdd(&bcur[tid], c) : 0;
    }
    __syncthreads();
    scnt[tid] = 0;
    __syncthreads();
#pragma unroll
    for (int it = 0; it < CH / 256; ++it) {
        int e = base + it * 256 + tid;
        if (e >= E) continue;
        int d = dst[e];
        int b = d >> 8;
        int p = sbase[b] + atomicAdd(&scnt[b], 1);
        ebuf[p] = ((u32)(d & 255) << 24) | ((u32)et[e] << 21) | (u32)src[e];
    }
}

// one block per bucket: 2048-bin (dstlo,r) counting sort -> offs2 + rowidx2(src)
__global__ __launch_bounds__(256)
void csr_emit2(const u32* __restrict__ ebuf, const int* __restrict__ bstart,
               int* __restrict__ offs2, int* __restrict__ rowidx2, int N, int R_) {
    __shared__ int hist[2048];
    __shared__ int cur[2048];
    __shared__ int wpart[4];
    __shared__ int carry_s;
    int b = blockIdx.x, tid = threadIdx.x;
    int lo = bstart[b], hi = bstart[b + 1];
    for (int k = tid; k < 2048; k += 256) { hist[k] = 0; cur[k] = 0; }
    if (tid == 0) carry_s = 0;
    __syncthreads();
    for (int i = lo + tid; i < hi; i += 256) atomicAdd(&hist[ebuf[i] >> 21], 1);
    __syncthreads();
    int lane = tid & 63, wid = tid >> 6;
    for (int c = 0; c < 8; ++c) {                 // exclusive scan of 2048 in place
        int v = hist[c * 256 + tid];
        int s = v;
#pragma unroll
        for (int off = 1; off < 64; off <<= 1) {
            int t = __shfl_up(s, off, 64);
            if (lane >= off) s += t;
        }
        if (lane == 63) wpart[wid] = s;
        __syncthreads();
        int add = 0;
        for (int w = 0; w < wid; ++w) add += wpart[w];
        int cbase = carry_s;
        __syncthreads();
        hist[c * 256 + tid] = cbase + add + s - v;
        if (tid == 255) carry_s = cbase + add + s;
        __syncthreads();
    }
    for (int k = tid; k < 2048; k += 256) {
        int dlo = k >> 3, r = k & 7;
        int d = (b << 8) + dlo;
        if (d < N && r < R_) offs2[d * R_ + r] = lo + hist[k];
    }
    __syncthreads();
    for (int i = lo + tid; i < hi; i += 256) {
        u32 rec = ebuf[i];
        int key = rec >> 21;
        int p = lo + hist[key] + atomicAdd(&cur[key], 1);
        rowidx2[p] = (int)(rec & 0x1FFFFFu);
    }
}

// ==== fused layer: block = 128 dsts x 128 out-cols ====
// acc = sum_r (sum_{e in N_r(d)} X[src]) @ W_r  +  X[d] @ loopW  (+ bias)
// mode 0: relu -> bf16 out ; mode 1: L2-normalize -> out (dtype per flag)
__global__ __launch_bounds__(256)
void fused_layer(const u16* __restrict__ Xc, const u16* __restrict__ Xo,
                 const u16* __restrict__ Wc, const u16* __restrict__ Wo,
                 const u16* __restrict__ lWc, const u16* __restrict__ lWo,
                 const u16* __restrict__ bc, const u16* __restrict__ bo,
                 const int* __restrict__ flag,
                 const int* __restrict__ offs2, const int* __restrict__ rowidx2,
                 void* __restrict__ out, int M, int R_, int mode)
{
    __shared__ u16 S[128 * 128];    // 32 KB gather tile (16B-chunk XOR swizzle)
    __shared__ u16 SL[128 * 128];   // 32 KB self-loop tile (same swizzle)
    const bool f = (*flag != 0);
    const u16* X     = f ? Xc  : Xo;
    const u16* Wall  = f ? Wc  : Wo;
    const u16* loopW = f ? lWc : lWo;
    const u16* bias  = f ? bc  : bo;

    const int row0 = blockIdx.x * 128;
    const int tid  = threadIdx.x;
    const int lane = tid & 63, wv = tid >> 6, quad = lane >> 4, l16 = lane & 15;
    const int d_loc = tid >> 1, half = tid & 1;
    const int dg = row0 + d_loc;

    // kick off self-loop A-tile staging now; completes before phase R_'s barrier
    {
        int r_base = (wv << 2) + (lane >> 4);
        int c      = lane & 15;
        auto* lds0 = (__attribute__((address_space(3))) char*)SL;
#pragma unroll
        for (int it = 0; it < 8; ++it) {
            int rl = it * 16 + r_base;
            int cg = c ^ (rl & 15);
            int rg = row0 + rl; if (rg >= M) rg = M - 1;
            const u16* gp = X + (long long)rg * D + cg * 8;
            __builtin_amdgcn_global_load_lds(
                (const __attribute__((address_space(1))) void*)gp,
                (__attribute__((address_space(3))) void*)(lds0 + it * 4096 + wv * 1024),
                16, 0, 0);
        }
    }

    f32x4 acc[8][2];
#pragma unroll
    for (int mt = 0; mt < 8; ++mt) { acc[mt][0] = (f32x4)0.f; acc[mt][1] = (f32x4)0.f; }

    const u32* X32 = (const u32*)X;

    for (int r = 0; r <= R_; ++r) {
        const u16* B = (r < R_) ? (Wall + (long long)r * D * D) : loopW;
        if (r < R_) {
            // gather-sum this dst's type-r in-neighbors (thread owns 64 features)
            float ga[64];
#pragma unroll
            for (int k = 0; k < 64; ++k) ga[k] = 0.f;
            if (dg < M) {
                int j0 = offs2[dg * R_ + r], j1 = offs2[dg * R_ + r + 1];
                for (int j = j0; j < j1; ++j) {
                    int s = rowidx2[j];
                    const u32x4* xr = (const u32x4*)(X32 + (long long)s * 64 + half * 32);
#pragma unroll
                    for (int q = 0; q < 8; ++q) {
                        u32x4 u = xr[q];
#pragma unroll
                        for (int m2 = 0; m2 < 4; ++m2) {
                            float lo_, hi_;
                            unpack2(u[m2], lo_, hi_);
                            ga[(q * 4 + m2) * 2]     += lo_;
                            ga[(q * 4 + m2) * 2 + 1] += hi_;
                        }
                    }
                }
            }
            __syncthreads();   // prior phase's MFMA reads of S are done
            // pack + swizzled store: global chunk g at LDS chunk g^(row&15)
#pragma unroll
            for (int q = 0; q < 8; ++q) {
                int g  = half * 8 + q;
                int gs = g ^ (d_loc & 15);
                u32x4 w;
#pragma unroll
                for (int m2 = 0; m2 < 4; ++m2)
                    w[m2] = pack_bf2(ga[(q * 4 + m2) * 2], ga[(q * 4 + m2) * 2 + 1]);
                *(u32x4*)((char*)S + d_loc * 256 + gs * 16) = w;
            }
            __syncthreads();
        } else {
            __syncthreads();   // drains global_load_lds (vmcnt) for SL
        }
        const u16* As_ = (r < R_) ? S : SL;

        // paired-col B frags: frag nt holds actual col wv*32 + 2*l16 + nt at slot n=l16
        s16x8 bf[4][2];
#pragma unroll
        for (int kk = 0; kk < 4; ++kk)
#pragma unroll
            for (int j = 0; j < 8; ++j) {
                u32 p = *(const u32*)(B + (kk * 32 + quad * 8 + j) * D + wv * 32 + 2 * l16);
                bf[kk][0][j] = (short)(p & 0xffffu);
                bf[kk][1][j] = (short)(p >> 16);
            }
#pragma unroll
        for (int kk = 0; kk < 4; ++kk) {
            const int chunk = (kk * 4 + quad) ^ l16;
#pragma unroll
            for (int mt = 0; mt < 8; ++mt) {
                int rl = mt * 16 + l16;
                s16x8 a = *(const s16x8*)(As_ + rl * D + chunk * 8);
                acc[mt][0] = __builtin_amdgcn_mfma_f32_16x16x32_bf16(a, bf[kk][0], acc[mt][0], 0, 0, 0);
                acc[mt][1] = __builtin_amdgcn_mfma_f32_16x16x32_bf16(a, bf[kk][1], acc[mt][1], 0, 0, 0);
            }
        }
        // next phase's S writes are fenced by the barrier at top of next iteration
    }

    // ---- epilogue ----
    float b0 = bf2f(bias[wv * 32 + 2 * l16]);
    float b1 = bf2f(bias[wv * 32 + 2 * l16 + 1]);
    int cpair = wv * 16 + l16;
    if (mode == 0) {
        u32* o = (u32*)out;
#pragma unroll
        for (int mt = 0; mt < 8; ++mt)
#pragma unroll
            for (int i = 0; i < 4; ++i) {
                int rr = row0 + mt * 16 + quad * 4 + i;
                if (rr >= M) continue;
                float v0 = fmaxf(acc[mt][0][i] + b0, 0.f);
                float v1 = fmaxf(acc[mt][1][i] + b1, 0.f);
                o[(long long)rr * 64 + cpair] = pack_bf2(v0, v1);
            }
    } else {
        __syncthreads();
        u32* T = (u32*)S;   // reuse S as [128][64] u32 (bf16 pairs)
#pragma unroll
        for (int mt = 0; mt < 8; ++mt)
#pragma unroll
            for (int i = 0; i < 4; ++i) {
                int rl = mt * 16 + quad * 4 + i;
                T[rl * 64 + cpair] = pack_bf2(acc[mt][0][i] + b0, acc[mt][1][i] + b1);
            }
        __syncthreads();
        for (int rr = 0; rr < 32; ++rr) {       // wave wv handles rows wv*32..+31
            int rl = wv * 32 + rr;
            int dgr = row0 + rl;
            u32 u = T[rl * 64 + lane];
            float a0, a1; unpack2(u, a0, a1);
            float s = a0 * a0 + a1 * a1;
#pragma unroll
            for (int off = 32; off > 0; off >>= 1) s += __shfl_xor(s, off, 64);
            float sc = 1.f / fmaxf(sqrtf(s), 1e-12f);
            if (dgr < M) {
                if (f) {
                    f32x2 w; w[0] = a0 * sc; w[1] = a1 * sc;
                    ((f32x2*)out)[(long long)dgr * 64 + lane] = w;
                } else {
                    ((u32*)out)[(long long)dgr * 64 + lane] = pack_bf2(a0 * sc, a1 * sc);
                }
            }
        }
    }
}

static inline size_t align256(size_t x) { return (x + 255) & ~(size_t)255; }

extern "C" void kernel_launch(void* const* d_in, const int* in_sizes, int n_in,
                              void* d_out, int out_size, void* d_ws, size_t ws_size,
                              hipStream_t stream)
{
    const void* x_in   = d_in[0];
    const void* W1_in  = d_in[1];
    const void* lW1_in = d_in[2];
    const void* b1_in  = d_in[3];
    const void* W2_in  = d_in[4];
    const void* lW2_in = d_in[5];
    const void* b2_in  = d_in[6];
    const int* src = (const int*)d_in[7];
    const int* dst = (const int*)d_in[8];
    const int* et  = (const int*)d_in[9];

    const int N = in_sizes[0] / D;            // 50000
    const int E = in_sizes[7];                // 800000
    const int R = in_sizes[1] / (D * D);      // 8 (code assumes R<=8, N<2^21)

    const long long ND  = (long long)N * D;
    const long long RDD = (long long)R * D * D;
    const long long DDl = (long long)D * D;
    const int nbuck = (N + 255) >> 8;         // 196

    size_t off = 0;
    auto alloc = [&](size_t bytes) { size_t o = off; off = align256(off + bytes); return o; };
    size_t o_flag = alloc(256);
    size_t o_xc   = alloc((size_t)ND * 2);
    size_t o_W1   = alloc((size_t)RDD * 2);
    size_t o_lW1  = alloc((size_t)DDl * 2);
    size_t o_b1   = alloc((size_t)D * 2);
    size_t o_W2   = alloc((size_t)RDD * 2);
    size_t o_lW2  = alloc((size_t)DDl * 2);
    size_t o_b2   = alloc((size_t)D * 2);
    size_t o_h    = alloc((size_t)ND * 2);
    size_t o_off2 = alloc(((size_t)N * R + 1) * 4);
    size_t o_gcnt = alloc(1024);
    size_t o_bst  = alloc(1040 * 4);
    size_t o_bcur = alloc(1024);
    size_t o_ebuf = alloc((size_t)E * 4);
    size_t o_ridx = alloc((size_t)E * 4);
    (void)ws_size;   // ~60 MB total, well under proven capacity

    char* ws = (char*)d_ws;
    int* flag    = (int*)(ws + o_flag);
    u16* x_c     = (u16*)(ws + o_xc);
    u16* W1c     = (u16*)(ws + o_W1);
    u16* lW1c    = (u16*)(ws + o_lW1);
    u16* b1c     = (u16*)(ws + o_b1);
    u16* W2c     = (u16*)(ws + o_W2);
    u16* lW2c    = (u16*)(ws + o_lW2);
    u16* b2c     = (u16*)(ws + o_b2);
    u16* h       = (u16*)(ws + o_h);
    int* offs2   = (int*)(ws + o_off2);
    int* gcnt    = (int*)(ws + o_gcnt);
    int* bstart  = (int*)(ws + o_bst);
    int* bcur    = (int*)(ws + o_bcur);
    u32* ebuf    = (u32*)(ws + o_ebuf);
    int* rowidx2 = (int*)(ws + o_ridx);

    dim3 blk(256, 1, 1);
    int mb    = (N + 127) / 128;
    int nblkE = (E + CH - 1) / CH;
    auto cdiv = [](long long n) { return (u32)((n + 255) / 256); };

    detect_dtype<<<dim3(1), blk, 0, stream>>>((const u16*)x_in, flag);
    long long tot = ND + RDD + DDl + D + RDD + DDl + D;
    to_bf16_all<<<dim3(cdiv(tot)), blk, 0, stream>>>(
        x_in, W1_in, lW1_in, b1_in, W2_in, lW2_in, b2_in,
        x_c, W1c, lW1c, b1c, W2c, lW2c, b2c,
        ND, RDD, DDl, (long long)D, RDD, DDl, (long long)D, flag);

    // CSR2 build: per-(dst, relation) lists
    zero_ints<<<dim3(1), blk, 0, stream>>>(gcnt, nbuck);
    csr_count<<<dim3(nblkE), blk, 0, stream>>>(dst, gcnt, E, nbuck);
    csr_scan<<<dim3(1), blk, 0, stream>>>(gcnt, bstart, bcur, nbuck, N * R, E, offs2);
    csr_part<<<dim3(nblkE), blk, 0, stream>>>(src, dst, et, bcur, ebuf, E, nbuck);
    csr_emit2<<<dim3(nbuck), blk, 0, stream>>>(ebuf, bstart, offs2, rowidx2, N, R);

    // layer 1: h = relu(gather-sum @ W1 + x@loopW1 + b1)
    fused_layer<<<dim3(mb), blk, 0, stream>>>(
        x_c, (const u16*)x_in, W1c, (const u16*)W1_in, lW1c, (const u16*)lW1_in,
        b1c, (const u16*)b1_in, flag, offs2, rowidx2, h, N, R, 0);

    // layer 2: out = l2norm(gather-sum @ W2 + h@loopW2 + b2)
    fused_layer<<<dim3(mb), blk, 0, stream>>>(
        h, h, W2c, (const u16*)W2_in, lW2c, (const u16*)lW2_in,
        b2c, (const u16*)b2_in, flag, offs2, rowidx2, d_out, N, R, 1);
}

// Round 7
// 290.645 us; speedup vs baseline: 1.1709x; 1.1709x over previous
//
#include <hip/hip_runtime.h>
#include <hip/hip_bf16.h>

#define D 128
#define CH 4096   // edges per block in CSR partition passes

typedef unsigned int u32;
typedef unsigned short u16;
typedef __attribute__((ext_vector_type(8))) short s16x8;
typedef __attribute__((ext_vector_type(4))) float f32x4;
typedef __attribute__((ext_vector_type(2))) float f32x2;
typedef __attribute__((ext_vector_type(2))) u32 u32x2;

__device__ __forceinline__ float bf2f(u16 u) {
    union { u32 u; float f; } v; v.u = ((u32)u) << 16; return v.f;
}
__device__ __forceinline__ u16 f2bf(float f) {
    union { float f; u32 u; } v; v.f = f;
    return (u16)((v.u + 0x7fffu + ((v.u >> 16) & 1u)) >> 16);
}
__device__ __forceinline__ u32 pack_bf2(float a, float b) {
    __hip_bfloat162 t = __float22bfloat162_rn(make_float2(a, b));
    union { __hip_bfloat162 t; u32 u; } v; v.t = t; return v.u;
}
__device__ __forceinline__ void unpack2(u32 u, float& lo, float& hi) {
    union { u32 u; float f; } a, b;
    a.u = u << 16; b.u = u & 0xffff0000u;
    lo = a.f; hi = b.f;
}

// ---- dtype detector (also zeroes gcnt for the CSR build) ----
__global__ void detect_dtype(const u16* __restrict__ x, int* __restrict__ flag,
                             int* __restrict__ gcnt, int nbuck) {
    __shared__ int cnt;
    if (threadIdx.x == 0) cnt = 0;
    __syncthreads();
    if ((int)threadIdx.x < nbuck) gcnt[threadIdx.x] = 0;
    u16 u = x[2 * threadIdx.x];
    int e = (u >> 7) & 0xFF;
    if (e >= 96 && e <= 150) atomicAdd(&cnt, 1);
    __syncthreads();
    if (threadIdx.x == 0) *flag = (cnt >= 128) ? 0 : 1;
}

// ---- canonicalize (body only runs when inputs are fp32) ----
__global__ __launch_bounds__(256)
void to_bf16_all(const void* __restrict__ s0, const void* __restrict__ s1,
                 const void* __restrict__ s2, const void* __restrict__ s3,
                 const void* __restrict__ s4, const void* __restrict__ s5,
                 const void* __restrict__ s6,
                 u16* __restrict__ d0, u16* __restrict__ d1, u16* __restrict__ d2,
                 u16* __restrict__ d3, u16* __restrict__ d4, u16* __restrict__ d5,
                 u16* __restrict__ d6,
                 long long n0, long long n1, long long n2, long long n3,
                 long long n4, long long n5, long long n6,
                 const int* __restrict__ flag)
{
    if (*flag == 0) return;
    long long i = (long long)blockIdx.x * 256 + threadIdx.x;
    const void* s; u16* d; long long off;
    if      (i < n0)                   { s = s0; d = d0; off = i; }
    else if (i < n0+n1)                { s = s1; d = d1; off = i-n0; }
    else if (i < n0+n1+n2)             { s = s2; d = d2; off = i-n0-n1; }
    else if (i < n0+n1+n2+n3)          { s = s3; d = d3; off = i-n0-n1-n2; }
    else if (i < n0+n1+n2+n3+n4)       { s = s4; d = d4; off = i-n0-n1-n2-n3; }
    else if (i < n0+n1+n2+n3+n4+n5)    { s = s5; d = d5; off = i-n0-n1-n2-n3-n4; }
    else if (i < n0+n1+n2+n3+n4+n5+n6) { s = s6; d = d6; off = i-n0-n1-n2-n3-n4-n5; }
    else return;
    d[off] = f2bf(((const float*)s)[off]);
}

// ==== bucketed CSR build: bucket = dst>>8 (needs N<=65536, R*N<2^24) ====
__global__ __launch_bounds__(256)
void csr_count(const int* __restrict__ dst, int* __restrict__ gcnt, int E, int nbuck) {
    __shared__ int scnt[256];
    int tid = threadIdx.x;
    scnt[tid] = 0;
    __syncthreads();
    int base = blockIdx.x * CH;
#pragma unroll
    for (int it = 0; it < CH / 256; ++it) {
        int e = base + it * 256 + tid;
        if (e < E) atomicAdd(&scnt[dst[e] >> 8], 1);
    }
    __syncthreads();
    if (tid < nbuck && scnt[tid] > 0) atomicAdd(&gcnt[tid], scnt[tid]);
}

__global__ __launch_bounds__(256)
void csr_scan(const int* __restrict__ gcnt, int* __restrict__ bstart, int* __restrict__ bcur,
              int nbuck, int N_, int E_, int* __restrict__ offs) {
    __shared__ int wpart[4];
    int tid = threadIdx.x, lane = tid & 63, wid = tid >> 6;
    int v = (tid < nbuck) ? gcnt[tid] : 0;
    int s = v;
#pragma unroll
    for (int off = 1; off < 64; off <<= 1) {
        int t = __shfl_up(s, off, 64);
        if (lane >= off) s += t;
    }
    if (lane == 63) wpart[wid] = s;
    __syncthreads();
    int add = 0;
    for (int w = 0; w < wid; ++w) add += wpart[w];
    int excl = add + s - v;
    if (tid <= nbuck) bstart[tid] = excl;
    if (tid < nbuck)  bcur[tid]  = excl;
    if (tid == 0) offs[N_] = E_;
}

// partition edges into bucket-contiguous ebuf; rec = (dst&255)<<24 | (et*N+src)
__global__ __launch_bounds__(256)
void csr_part(const int* __restrict__ src, const int* __restrict__ dst,
              const int* __restrict__ et, int* __restrict__ bcur,
              u32* __restrict__ ebuf, int E, int N, int nbuck) {
    __shared__ int scnt[256], sbase[256];
    int tid = threadIdx.x;
    scnt[tid] = 0;
    __syncthreads();
    int base = blockIdx.x * CH;
#pragma unroll
    for (int it = 0; it < CH / 256; ++it) {
        int e = base + it * 256 + tid;
        if (e < E) atomicAdd(&scnt[dst[e] >> 8], 1);
    }
    __syncthreads();
    if (tid < nbuck) {
        int c = scnt[tid];
        sbase[tid] = c ? atomicAdd(&bcur[tid], c) : 0;
    }
    __syncthreads();
    scnt[tid] = 0;
    __syncthreads();
#pragma unroll
    for (int it = 0; it < CH / 256; ++it) {
        int e = base + it * 256 + tid;
        if (e >= E) continue;
        int d = dst[e];
        int b = d >> 8;
        int p = sbase[b] + atomicAdd(&scnt[b], 1);
        ebuf[p] = ((u32)(d & 255) << 24) | (u32)(et[e] * N + src[e]);
    }
}

// one block per bucket: 256-bin dstlo counting sort -> offs + rowidx
__global__ __launch_bounds__(256)
void csr_emit(const u32* __restrict__ ebuf, const int* __restrict__ bstart,
              int* __restrict__ offs, int* __restrict__ rowidx, int N) {
    __shared__ int hist[256], excl[256], cur[256];
    __shared__ int wpart[4];
    int b = blockIdx.x, tid = threadIdx.x;
    int lo = bstart[b], hi = bstart[b + 1];
    hist[tid] = 0; cur[tid] = 0;
    __syncthreads();
    for (int i = lo + tid; i < hi; i += 256) atomicAdd(&hist[ebuf[i] >> 24], 1);
    __syncthreads();
    int lane = tid & 63, wid = tid >> 6;
    int v = hist[tid], s = v;
#pragma unroll
    for (int off = 1; off < 64; off <<= 1) {
        int t = __shfl_up(s, off, 64);
        if (lane >= off) s += t;
    }
    if (lane == 63) wpart[wid] = s;
    __syncthreads();
    int add = 0;
    for (int w = 0; w < wid; ++w) add += wpart[w];
    int e_ = add + s - v;
    excl[tid] = e_;
    int node = (b << 8) + tid;
    if (node < N) offs[node] = lo + e_;
    __syncthreads();
    for (int i = lo + tid; i < hi; i += 256) {
        u32 rec = ebuf[i];
        int dl = rec >> 24;
        int p = lo + excl[dl] + atomicAdd(&cur[dl], 1);
        rowidx[p] = (int)(rec & 0xFFFFFFu);
    }
}

// ---- GEMM: C[M,128] = A @ B ; LDS-staged A (global_load_lds w=16, XOR-swizzle) ----
__global__ __launch_bounds__(256)
void gemm_k128(const u16* __restrict__ Ac, const u16* __restrict__ Ao,
               const u16* __restrict__ Wc, const u16* __restrict__ Wo,
               const u16* __restrict__ lWc, const u16* __restrict__ lWo,
               const u16* __restrict__ bc, const u16* __restrict__ bo,
               const int* __restrict__ flag,
               int M, int R_, u16* __restrict__ xw, u16* __restrict__ sl)
{
    __shared__ u16 As[128 * 128];
    const bool f = (*flag != 0);
    const u16* A     = f ? Ac  : Ao;
    const u16* Wall  = f ? Wc  : Wo;
    const u16* loopW = f ? lWc : lWo;
    const u16* bias  = f ? bc  : bo;

    const int y = blockIdx.y;
    const u16* B = (y < R_) ? (Wall + (long long)y * D * D) : loopW;
    const int row0 = blockIdx.x * 128;
    const int tid  = threadIdx.x;
    const int lane = tid & 63;
    const int wv   = tid >> 6;
    const int quad = lane >> 4;
    const int l16  = lane & 15;

    {
        int r_base = (wv << 2) + (lane >> 4);
        int c      = lane & 15;
        auto* lds0 = (__attribute__((address_space(3))) char*)As;
#pragma unroll
        for (int it = 0; it < 8; ++it) {
            int rl = it * 16 + r_base;
            int cg = c ^ (rl & 15);
            int rg = row0 + rl; if (rg >= M) rg = M - 1;
            const u16* gp = A + (long long)rg * D + cg * 8;
            __builtin_amdgcn_global_load_lds(
                (const __attribute__((address_space(1))) void*)gp,
                (__attribute__((address_space(3))) void*)(lds0 + it * 4096 + wv * 1024),
                16, 0, 0);
        }
    }

    s16x8 bf[4][2];
#pragma unroll
    for (int kk = 0; kk < 4; ++kk)
#pragma unroll
        for (int j = 0; j < 8; ++j) {
            u32 p = *(const u32*)(B + (kk * 32 + quad * 8 + j) * D + wv * 32 + 2 * l16);
            bf[kk][0][j] = (short)(p & 0xffffu);
            bf[kk][1][j] = (short)(p >> 16);
        }

    f32x4 acc[8][2];
#pragma unroll
    for (int mt = 0; mt < 8; ++mt) { acc[mt][0] = (f32x4)0.f; acc[mt][1] = (f32x4)0.f; }

    __syncthreads();

#pragma unroll
    for (int kk = 0; kk < 4; ++kk) {
        const int chunk = (kk * 4 + quad) ^ l16;
#pragma unroll
        for (int mt = 0; mt < 8; ++mt) {
            int rl = mt * 16 + l16;
            s16x8 a = *(const s16x8*)(As + rl * D + chunk * 8);
            acc[mt][0] = __builtin_amdgcn_mfma_f32_16x16x32_bf16(a, bf[kk][0], acc[mt][0], 0, 0, 0);
            acc[mt][1] = __builtin_amdgcn_mfma_f32_16x16x32_bf16(a, bf[kk][1], acc[mt][1], 0, 0, 0);
        }
    }

    long long MD64 = (long long)M * 64;
    int cpair = wv * 16 + l16;
    if (y < R_) {
        u32* o = (u32*)xw + (long long)y * MD64;
#pragma unroll
        for (int mt = 0; mt < 8; ++mt)
#pragma unroll
            for (int i = 0; i < 4; ++i) {
                int r = row0 + mt * 16 + quad * 4 + i;
                if (r >= M) continue;
                o[(long long)r * 64 + cpair] = pack_bf2(acc[mt][0][i], acc[mt][1][i]);
            }
    } else {
        float b0 = bf2f(bias[wv * 32 + 2 * l16]);
        float b1 = bf2f(bias[wv * 32 + 2 * l16 + 1]);
        u32* o = (u32*)sl;
#pragma unroll
        for (int mt = 0; mt < 8; ++mt)
#pragma unroll
            for (int i = 0; i < 4; ++i) {
                int r = row0 + mt * 16 + quad * 4 + i;
                if (r >= M) continue;
                o[(long long)r * 64 + cpair] = pack_bf2(acc[mt][0][i] + b0, acc[mt][1][i] + b1);
            }
    }
}

// ---- aggregate v2: one wave per dst node; half-wave per edge row ----
// lane = hi*32 + p : handles row (j + hi), u32s [2p, 2p+1] (features 4p..4p+3)
// main loop: 4 load instrs cover 8 edges (8 rows in flight per wave)
__global__ __launch_bounds__(256)
void aggregate(const u16* __restrict__ xw, const u16* __restrict__ sl,
               const int* __restrict__ offs, const int* __restrict__ rowidx,
               void* __restrict__ out, int N, int mode, const int* __restrict__ flag)
{
    int node = blockIdx.x * 4 + (threadIdx.x >> 6);
    int lane = threadIdx.x & 63;
    int p  = lane & 31;
    int hi = lane >> 5;
    if (node >= N) return;
    const u32x2* xw2 = (const u32x2*)xw;   // row stride = 32 u32x2

    float a0, a1, a2, a3;
    if (hi == 0) {
        u32x2 s2 = ((const u32x2*)sl)[(long long)node * 32 + p];
        unpack2(s2[0], a0, a1);
        unpack2(s2[1], a2, a3);
    } else { a0 = a1 = a2 = a3 = 0.f; }

    int j = offs[node], j1 = offs[node + 1];
    for (; j + 8 <= j1; j += 8) {
        int r0 = rowidx[j + 0 + hi];
        int r1 = rowidx[j + 2 + hi];
        int r2 = rowidx[j + 4 + hi];
        int r3 = rowidx[j + 6 + hi];
        u32x2 u0 = xw2[(long long)r0 * 32 + p];
        u32x2 u1 = xw2[(long long)r1 * 32 + p];
        u32x2 u2 = xw2[(long long)r2 * 32 + p];
        u32x2 u3 = xw2[(long long)r3 * 32 + p];
        float l, h;
        unpack2(u0[0], l, h); a0 += l; a1 += h;  unpack2(u0[1], l, h); a2 += l; a3 += h;
        unpack2(u1[0], l, h); a0 += l; a1 += h;  unpack2(u1[1], l, h); a2 += l; a3 += h;
        unpack2(u2[0], l, h); a0 += l; a1 += h;  unpack2(u2[1], l, h); a2 += l; a3 += h;
        unpack2(u3[0], l, h); a0 += l; a1 += h;  unpack2(u3[1], l, h); a2 += l; a3 += h;
    }
    for (; j < j1; j += 2) {
        bool ok = (j + hi < j1);
        int rr = rowidx[ok ? j + hi : j];
        u32x2 u = xw2[(long long)rr * 32 + p];
        if (!ok) { u[0] = 0; u[1] = 0; }
        float l, h;
        unpack2(u[0], l, h); a0 += l; a1 += h;
        unpack2(u[1], l, h); a2 += l; a3 += h;
    }

    // combine the two half-wave partials (both halves end with the sum)
    a0 += __shfl_xor(a0, 32, 64);
    a1 += __shfl_xor(a1, 32, 64);
    a2 += __shfl_xor(a2, 32, 64);
    a3 += __shfl_xor(a3, 32, 64);

    if (mode == 0) {
        if (hi == 0) {
            u32x2 w;
            w[0] = pack_bf2(fmaxf(a0, 0.f), fmaxf(a1, 0.f));
            w[1] = pack_bf2(fmaxf(a2, 0.f), fmaxf(a3, 0.f));
            ((u32x2*)out)[(long long)node * 32 + p] = w;
        }
    } else {
        float s = a0 * a0 + a1 * a1 + a2 * a2 + a3 * a3;
#pragma unroll
        for (int off = 16; off > 0; off >>= 1) s += __shfl_xor(s, off, 64);
        float sc = 1.f / fmaxf(sqrtf(s), 1e-12f);
        if (hi == 0) {
            if (*flag) {
                f32x4 w; w[0] = a0 * sc; w[1] = a1 * sc; w[2] = a2 * sc; w[3] = a3 * sc;
                ((f32x4*)out)[(long long)node * 32 + p] = w;
            } else {
                u32x2 w;
                w[0] = pack_bf2(a0 * sc, a1 * sc);
                w[1] = pack_bf2(a2 * sc, a3 * sc);
                ((u32x2*)out)[(long long)node * 32 + p] = w;
            }
        }
    }
}

static inline size_t align256(size_t x) { return (x + 255) & ~(size_t)255; }

extern "C" void kernel_launch(void* const* d_in, const int* in_sizes, int n_in,
                              void* d_out, int out_size, void* d_ws, size_t ws_size,
                              hipStream_t stream)
{
    const void* x_in   = d_in[0];
    const void* W1_in  = d_in[1];
    const void* lW1_in = d_in[2];
    const void* b1_in  = d_in[3];
    const void* W2_in  = d_in[4];
    const void* lW2_in = d_in[5];
    const void* b2_in  = d_in[6];
    const int* src = (const int*)d_in[7];
    const int* dst = (const int*)d_in[8];
    const int* et  = (const int*)d_in[9];

    const int N = in_sizes[0] / D;            // 50000
    const int E = in_sizes[7];                // 800000
    const int R = in_sizes[1] / (D * D);      // 8
    const int nbuck = (N + 255) >> 8;         // 196

    const long long ND  = (long long)N * D;
    const long long RDD = (long long)R * D * D;
    const long long DDl = (long long)D * D;

    size_t off = 0;
    auto alloc = [&](size_t bytes) { size_t o = off; off = align256(off + bytes); return o; };
    size_t o_flag = alloc(256);
    size_t o_xc   = alloc((size_t)ND * 2);
    size_t o_W1   = alloc((size_t)RDD * 2);
    size_t o_lW1  = alloc((size_t)DDl * 2);
    size_t o_b1   = alloc((size_t)D * 2);
    size_t o_W2   = alloc((size_t)RDD * 2);
    size_t o_lW2  = alloc((size_t)DDl * 2);
    size_t o_b2   = alloc((size_t)D * 2);
    size_t o_sl   = alloc((size_t)ND * 2);
    size_t o_h    = alloc((size_t)ND * 2);
    size_t o_offs = alloc((size_t)(N + 1) * 4);
    size_t o_gcnt = alloc(1024);
    size_t o_bst  = alloc(1040 * 4);
    size_t o_bcur = alloc(1024);
    size_t o_ebuf = alloc((size_t)E * 4);
    size_t o_ridx = alloc((size_t)E * 4);
    size_t o_xw   = alloc((size_t)R * ND * 2);
    (void)ws_size;

    char* ws = (char*)d_ws;
    int* flag   = (int*)(ws + o_flag);
    u16* x_c    = (u16*)(ws + o_xc);
    u16* W1c    = (u16*)(ws + o_W1);
    u16* lW1c   = (u16*)(ws + o_lW1);
    u16* b1c    = (u16*)(ws + o_b1);
    u16* W2c    = (u16*)(ws + o_W2);
    u16* lW2c   = (u16*)(ws + o_lW2);
    u16* b2c    = (u16*)(ws + o_b2);
    u16* sl     = (u16*)(ws + o_sl);
    u16* h      = (u16*)(ws + o_h);
    int* offs   = (int*)(ws + o_offs);
    int* gcnt   = (int*)(ws + o_gcnt);
    int* bstart = (int*)(ws + o_bst);
    int* bcur   = (int*)(ws + o_bcur);
    u32* ebuf   = (u32*)(ws + o_ebuf);
    int* rowidx = (int*)(ws + o_ridx);
    u16* xw     = (u16*)(ws + o_xw);

    dim3 blk(256, 1, 1);
    int mb    = (N + 127) / 128;
    int nblkE = (E + CH - 1) / CH;
    auto cdiv = [](long long n) { return (u32)((n + 255) / 256); };

    detect_dtype<<<dim3(1), blk, 0, stream>>>((const u16*)x_in, flag, gcnt, nbuck);
    long long tot = ND + RDD + DDl + D + RDD + DDl + D;
    to_bf16_all<<<dim3(cdiv(tot)), blk, 0, stream>>>(
        x_in, W1_in, lW1_in, b1_in, W2_in, lW2_in, b2_in,
        x_c, W1c, lW1c, b1c, W2c, lW2c, b2c,
        ND, RDD, DDl, (long long)D, RDD, DDl, (long long)D, flag);

    // CSR build (bucketed counting sort)
    csr_count<<<dim3(nblkE), blk, 0, stream>>>(dst, gcnt, E, nbuck);
    csr_scan<<<dim3(1), blk, 0, stream>>>(gcnt, bstart, bcur, nbuck, N, E, offs);
    csr_part<<<dim3(nblkE), blk, 0, stream>>>(src, dst, et, bcur, ebuf, E, N, nbuck);
    csr_emit<<<dim3(nbuck), blk, 0, stream>>>(ebuf, bstart, offs, rowidx, N);

    // layer 1
    gemm_k128<<<dim3(mb, R + 1), blk, 0, stream>>>(
        x_c, (const u16*)x_in, W1c, (const u16*)W1_in, lW1c, (const u16*)lW1_in,
        b1c, (const u16*)b1_in, flag, N, R, xw, sl);
    aggregate<<<dim3((N + 3) / 4), blk, 0, stream>>>(xw, sl, offs, rowidx, h, N, 0, flag);

    // layer 2
    gemm_k128<<<dim3(mb, R + 1), blk, 0, stream>>>(
        h, h, W2c, (const u16*)W2_in, lW2c, (const u16*)lW2_in,
        b2c, (const u16*)b2_in, flag, N, R, xw, sl);
    aggregate<<<dim3((N + 3) / 4), blk, 0, stream>>>(xw, sl, offs, rowidx, d_out, N, 1, flag);
}